// Round 2
// baseline (537.639 us; speedup 1.0000x reference)
//
#include <hip/hip_runtime.h>

#define NPTS (16*20480)
#define BM 32
#define NTILES (NPTS/BM)

typedef _Float16 f16;
typedef _Float16 f16x8 __attribute__((ext_vector_type(8)));
typedef float    f32x4 __attribute__((ext_vector_type(4)));

#define O_PTS   ((size_t)0)
#define O_GRASP ((size_t)NPTS*3)
#define O_S     (O_GRASP + (size_t)NPTS*16)
#define O_W     (O_S + (size_t)NPTS)
#define O_FEAT  (O_W + (size_t)NPTS)

struct Params {
  const float* point_feat;
  const float* points;
  const float* W1[4];
  const float* b1[4];
  const float* W2[4];
  const float* b2[4];
  float* out;
};

__launch_bounds__(512, 2)
__global__ void contactnet_fused(Params P)
{
  // LDS ≈ 93 KB -> 1 block/CU (8 waves = 2/SIMD)
  __shared__ float pf32[BM][132];      // [0..127] feat, [128..130] xyz
  __shared__ float h32[BM][548];       // head h at col head*136 + n; stride 548 -> bank 4p
  __shared__ float W2s[8][132];        // rows o=0:s,1..3:z1,4..6:z2,7:w
  __shared__ float b2s[8];
  __shared__ float out2[BM][8][2];
  __shared__ float gr[BM][16];

  const int t    = threadIdx.x;
  const int lane = t & 63;
  const int wv   = t >> 6;     // 0..7
  const int head = wv >> 1;    // wave's head
  const int half = wv & 1;     // which 64-hidden half
  const int l15  = lane & 15;
  const int lg   = lane >> 4;  // 0..3

  // ---- W2/b2 -> LDS (loop-invariant; synced by first in-loop barrier)
  for (int i = t; i < 8*128; i += 512) {
    int o = i >> 7, k = i & 127;
    int hd = (o + 2) / 3;
    int r  = o - (hd ? 3*hd - 2 : 0);
    W2s[o][k] = P.W2[hd][r*128 + k];
  }
  if (t < 8) {
    int o = t, hd = (o + 2) / 3, r = o - (hd ? 3*hd - 2 : 0);
    b2s[o] = P.b2[hd][r];
  }

  // ---- layer-1 weights -> registers, split fp16 hi/lo (feat cols 3..130).
  // xyz cols 0..2 kept exact fp32 (VALU path).
  float bias1[4];
  float w1x[4], w1y[4], w1z[4];
  f16x8 Wf_hi[4][4];   // [nt][kk]
  f16x8 Wf_lo[4][4];
  {
    const float* W1h = P.W1[head];
    const float* b1h = P.b1[head];
    #pragma unroll
    for (int nt = 0; nt < 4; ++nt) {
      int row = half*64 + nt*16 + l15;
      const float* wr = W1h + row*131;
      bias1[nt] = b1h[row];
      w1x[nt] = wr[0]; w1y[nt] = wr[1]; w1z[nt] = wr[2];
      #pragma unroll
      for (int kk = 0; kk < 4; ++kk) {
        f16x8 fh, fl;
        int k0 = 3 + kk*32 + lg*8;
        #pragma unroll
        for (int j = 0; j < 8; ++j) {
          float w = wr[k0 + j];
          f16 hi = (f16)w;
          fh[j] = hi;
          fl[j] = (f16)(w - (float)hi);
        }
        Wf_hi[nt][kk] = fh;
        Wf_lo[nt][kk] = fl;
      }
    }
  }

  for (int tile = blockIdx.x; tile < NTILES; tile += gridDim.x) {
    const int base = tile * BM;

    // ---- stage pf tile (fp32) + write feats_out / pts_out from the same regs
    #pragma unroll
    for (int r = 0; r < 2; ++r) {
      int f = t + r*512;               // 0..1023 float4s
      int p = f >> 5, c4 = f & 31;
      const f32x4 v = *(const f32x4*)(P.point_feat + ((size_t)(base+p)*128 + c4*4));
      *(f32x4*)&pf32[p][c4*4] = v;
      float* dst = P.out + O_FEAT + (size_t)(base+p)*131 + 3 + c4*4;
      dst[0] = v[0]; dst[1] = v[1]; dst[2] = v[2]; dst[3] = v[3];
    }
    if (t < 96) {
      int p = t / 3, c = t - p*3;
      float v = P.points[(size_t)base*3 + t];
      pf32[p][128 + c] = v;
      P.out[O_PTS + (size_t)base*3 + t] = v;
      P.out[O_FEAT + (size_t)(base+p)*131 + c] = v;
    }
    __syncthreads();

    // ---- layer 1: per wave 32pts x 64hid, split-fp16 MFMA 16x16x32
    f32x4 acc[2][4];
    #pragma unroll
    for (int mt = 0; mt < 2; ++mt)
      #pragma unroll
      for (int nt = 0; nt < 4; ++nt) {
        acc[mt][nt][0] = bias1[nt]; acc[mt][nt][1] = bias1[nt];
        acc[mt][nt][2] = bias1[nt]; acc[mt][nt][3] = bias1[nt];
      }

    // xyz contribution, exact fp32 VALU (C/D map: row=lg*4+r, col=l15)
    #pragma unroll
    for (int mt = 0; mt < 2; ++mt)
      #pragma unroll
      for (int r = 0; r < 4; ++r) {
        int m = mt*16 + lg*4 + r;
        float x = pf32[m][128], y = pf32[m][129], z = pf32[m][130];
        #pragma unroll
        for (int nt = 0; nt < 4; ++nt)
          acc[mt][nt][r] += x*w1x[nt] + y*w1y[nt] + z*w1z[nt];
      }

    #pragma unroll
    for (int kk = 0; kk < 4; ++kk) {
      f16x8 ah[2], al[2];
      #pragma unroll
      for (int mt = 0; mt < 2; ++mt) {
        int m  = mt*16 + l15;
        int k0 = kk*32 + lg*8;
        f32x4 v0 = *(const f32x4*)&pf32[m][k0];
        f32x4 v1 = *(const f32x4*)&pf32[m][k0+4];
        f16x8 h_, l_;
        #pragma unroll
        for (int j = 0; j < 4; ++j) {
          f16 hi = (f16)v0[j];
          h_[j] = hi; l_[j] = (f16)(v0[j] - (float)hi);
        }
        #pragma unroll
        for (int j = 0; j < 4; ++j) {
          f16 hi = (f16)v1[j];
          h_[4+j] = hi; l_[4+j] = (f16)(v1[j] - (float)hi);
        }
        ah[mt] = h_; al[mt] = l_;
      }
      #pragma unroll
      for (int mt = 0; mt < 2; ++mt)
        #pragma unroll
        for (int nt = 0; nt < 4; ++nt) {
          acc[mt][nt] = __builtin_amdgcn_mfma_f32_16x16x32_f16(ah[mt], Wf_hi[nt][kk], acc[mt][nt], 0, 0, 0);
          acc[mt][nt] = __builtin_amdgcn_mfma_f32_16x16x32_f16(al[mt], Wf_hi[nt][kk], acc[mt][nt], 0, 0, 0);
          acc[mt][nt] = __builtin_amdgcn_mfma_f32_16x16x32_f16(ah[mt], Wf_lo[nt][kk], acc[mt][nt], 0, 0, 0);
        }
    }

    // relu -> h32 LDS fp32 (C/D map: row=(lane>>4)*4+r, col=lane&15)
    #pragma unroll
    for (int mt = 0; mt < 2; ++mt)
      #pragma unroll
      for (int nt = 0; nt < 4; ++nt)
        #pragma unroll
        for (int r = 0; r < 4; ++r) {
          int prow = mt*16 + lg*4 + r;
          h32[prow][head*136 + half*64 + nt*16 + l15] = fmaxf(acc[mt][nt][r], 0.f);
        }
    __syncthreads();

    // ---- layer 2: 512 thr = (32 p) x (8 o) x (2 K-halves), fp32 VALU
    {
      int kh = t >> 8;
      int p  = (t >> 3) & 31;
      int o  = t & 7;
      int hd = (o + 2) / 3;
      float a2 = kh ? 0.f : b2s[o];
      const float* hp = &h32[p][hd*136 + kh*64];
      const float* wp = &W2s[o][kh*64];
      #pragma unroll
      for (int i = 0; i < 16; ++i) {
        f32x4 hv = *(const f32x4*)(hp + i*4);
        f32x4 wv = *(const f32x4*)(wp + i*4);
        a2 = fmaf(hv[0], wv[0], a2);
        a2 = fmaf(hv[1], wv[1], a2);
        a2 = fmaf(hv[2], wv[2], a2);
        a2 = fmaf(hv[3], wv[3], a2);
      }
      out2[p][o][kh] = a2;
    }
    __syncthreads();

    // ---- post-processing (fp32, 32 threads)
    if (t < BM) {
      const int p = t;
      float s   = out2[p][0][0] + out2[p][0][1];
      float z1x = out2[p][1][0] + out2[p][1][1];
      float z1y = out2[p][2][0] + out2[p][2][1];
      float z1z = out2[p][3][0] + out2[p][3][1];
      float z2x = out2[p][4][0] + out2[p][4][1];
      float z2y = out2[p][5][0] + out2[p][5][1];
      float z2z = out2[p][6][0] + out2[p][6][1];
      float w   = out2[p][7][0] + out2[p][7][1];
      float px = pf32[p][128], py = pf32[p][129], pz = pf32[p][130];

      float n1 = sqrtf(z1x*z1x + z1y*z1y + z1z*z1z);
      z1x /= n1; z1y /= n1; z1z /= n1;
      float d12 = z1x*z2x + z1y*z2y + z1z*z2z;
      z2x -= d12*z1x; z2y -= d12*z1y; z2z -= d12*z1z;
      float n2 = sqrtf(z2x*z2x + z2y*z2y + z2z*z2z);
      z2x /= n2; z2y /= n2; z2z /= n2;
      w = fminf(fmaxf(w, -0.08f), 0.08f);

      float nb = sqrtf(z1x*z1x + z1y*z1y + z1z*z1z);
      float bx = z1x/nb, by = z1y/nb, bz = z1z/nb;
      float inner = bx*z2x + by*z2y + bz*z2z;
      float na2 = sqrtf(z2x*z2x + z2y*z2y + z2z*z2z);
      float ax = (z2x - inner*bx)/na2, ay = (z2y - inner*by)/na2, az = (z2z - inner*bz)/na2;
      float nbn = sqrtf(bx*bx + by*by + bz*bz);
      float bnx = bx/nbn, bny = by/nbn, bnz = bz/nbn;
      float nan2 = sqrtf(ax*ax + ay*ay + az*az);
      float anx = ax/nan2, any_ = ay/nan2, anz = az/nan2;
      float cx = any_*bnz - anz*bny;
      float cy = anz*bnx - anx*bnz;
      float cz = anx*bny - any_*bnx;
      float nc = sqrtf(cx*cx + cy*cy + cz*cz);
      float gx = cx/nc, gyv = cy/nc, gzv = cz/nc;
      float tx = px - 0.1034f*anx + 0.5f*w*bnx;
      float ty = py - 0.1034f*any_ + 0.5f*w*bny;
      float tz = pz - 0.1034f*anz + 0.5f*w*bnz;

      gr[p][0]=bnx; gr[p][1]=gx;  gr[p][2]=anx;  gr[p][3]=tx;
      gr[p][4]=bny; gr[p][5]=gyv; gr[p][6]=any_; gr[p][7]=ty;
      gr[p][8]=bnz; gr[p][9]=gzv; gr[p][10]=anz; gr[p][11]=tz;
      gr[p][12]=0.f; gr[p][13]=0.f; gr[p][14]=0.f; gr[p][15]=1.f;

      P.out[O_S + base + p] = s;
      P.out[O_W + base + p] = fmaxf(w, 0.f);
    }
    __syncthreads();

    // ---- coalesced grasp writes (512 floats = 32x16)
    P.out[O_GRASP + (size_t)base*16 + t] = gr[t >> 4][t & 15];
    __syncthreads();
  }
}

extern "C" void kernel_launch(void* const* d_in, const int* in_sizes, int n_in,
                              void* d_out, int out_size, void* d_ws, size_t ws_size,
                              hipStream_t stream) {
  Params P;
  P.point_feat = (const float*)d_in[0];
  P.points     = (const float*)d_in[1];
  // d_in[2] = batch ids (unused; B is static)
  int idx = 3;
  for (int h = 0; h < 4; ++h) {
    P.W1[h] = (const float*)d_in[idx + 0];
    P.b1[h] = (const float*)d_in[idx + 1];
    P.W2[h] = (const float*)d_in[idx + 2];
    P.b2[h] = (const float*)d_in[idx + 3];
    idx += 4;
  }
  P.out = (float*)d_out;
  contactnet_fused<<<dim3(512), dim3(512), 0, stream>>>(P);
}